// Round 3
// baseline (737.710 us; speedup 1.0000x reference)
//
#include <hip/hip_runtime.h>

namespace {

constexpr int kN  = 20000;
constexpr int kE  = 80000;
constexpr int kIn = 64;
constexpr int kH  = 32;
constexpr int kEA = 32;
constexpr int kT  = 64;
constexpr int kL  = 3;
constexpr float kEps = 1e-5f;

typedef __attribute__((ext_vector_type(8))) short bf16x8;
typedef __attribute__((ext_vector_type(4))) float f32x4;

__device__ inline unsigned short f2bf(float f) {
  unsigned u = __builtin_bit_cast(unsigned, f);
  unsigned r = (u + 0x7fff + ((u >> 16) & 1)) >> 16;  // RNE
  return (unsigned short)r;
}
__device__ inline float bf2f(short s) {
  unsigned u = ((unsigned)(unsigned short)s) << 16;
  return __builtin_bit_cast(float, u);
}

// ---- pack Wm[l] f32[32][1024] -> B-fragment-ordered bf16: frag[l][ct][lane][8]
// tile ct covers cols [16ct,16ct+16); lane: col = 16ct+(lane&15), k = (lane>>4)*8+j
__global__ __launch_bounds__(256) void pack_w(const float* __restrict__ emW,
                                              unsigned short* __restrict__ wbf) {
  const int idx = blockIdx.x * 256 + threadIdx.x;
  if (idx >= kL * 64 * 64) return;
  const int lane = idx & 63, ct = (idx >> 6) & 63, l = idx >> 12;
  const int k0 = (lane >> 4) * 8, c = ct * 16 + (lane & 15);
  const float* W = emW + (size_t)l * kEA * kH * kH;
  unsigned out[4];
#pragma unroll
  for (int p = 0; p < 4; ++p) {
    unsigned lo = f2bf(W[(size_t)(k0 + 2 * p) * (kH * kH) + c]);
    unsigned hi = f2bf(W[(size_t)(k0 + 2 * p + 1) * (kH * kH) + c]);
    out[p] = lo | (hi << 16);
  }
  *reinterpret_cast<uint4*>(wbf + (size_t)idx * 8) =
      make_uint4(out[0], out[1], out[2], out[3]);
}

// ---------------- h = x @ initW + initb ----------------
__global__ __launch_bounds__(256) void init_proj(
    const float* __restrict__ x, const float* __restrict__ W,
    const float* __restrict__ b, float* __restrict__ h) {
  __shared__ float Wl[kIn * kH];
  __shared__ float bl[kH];
  const int tid = threadIdx.x;
  for (int j = tid; j < kIn * kH; j += 256) Wl[j] = W[j];
  if (tid < kH) bl[tid] = b[tid];
  __syncthreads();
  const int node = blockIdx.x * 256 + tid;
  if (node >= kN) return;
  float xr[kIn];
  const float4* xp = reinterpret_cast<const float4*>(x + (size_t)node * kIn);
#pragma unroll
  for (int k4 = 0; k4 < kIn / 4; ++k4) {
    float4 v = xp[k4];
    xr[k4 * 4 + 0] = v.x; xr[k4 * 4 + 1] = v.y;
    xr[k4 * 4 + 2] = v.z; xr[k4 * 4 + 3] = v.w;
  }
  float* hp = h + (size_t)node * kH;
#pragma unroll
  for (int o = 0; o < kH; ++o) {
    float acc = bl[o];
#pragma unroll
    for (int k = 0; k < kIn; ++k) acc = fmaf(xr[k], Wl[k * kH + o], acc);
    hp[o] = acc;
  }
}

// ------------- MFMA edge MLP + message + scatter-add -------------
// block = 256 edges, 4 waves; wave w owns i in [8w, 8w+8) (col tiles w*16..w*16+15)
constexpr int AP = 40;  // attr/h LDS row pitch in ushorts (80 B)
constexpr int MP = 36;  // msg LDS row pitch in f32 (144 B)
__global__ __launch_bounds__(256) void edge_msg_mfma(
    const float* __restrict__ attr, const int* __restrict__ ei,
    const float* __restrict__ h, const unsigned short* __restrict__ wbf,
    const float* __restrict__ bm, float* __restrict__ agg) {
  __shared__ unsigned short attr_s[256 * AP];  // 20 KB bf16
  __shared__ unsigned short h_s[256 * AP];     // 20 KB bf16
  __shared__ float msg_s[256 * MP];            // 36 KB f32
  const int tid = threadIdx.x;
  const int e = blockIdx.x * 256 + tid;
  const bool act = e < kE;
  int dst = 0;

  for (int j = tid; j < 256 * MP; j += 256) msg_s[j] = 0.f;

  if (act) {
    dst = ei[kE + e];
    const int src = ei[e];
    const float4* ap = reinterpret_cast<const float4*>(attr + (size_t)e * kEA);
    const float4* hp = reinterpret_cast<const float4*>(h + (size_t)src * kH);
#pragma unroll
    for (int q = 0; q < 8; ++q) {
      float4 va = ap[q];
      float4 vh = hp[q];
      uint2 pa = make_uint2(f2bf(va.x) | ((unsigned)f2bf(va.y) << 16),
                            f2bf(va.z) | ((unsigned)f2bf(va.w) << 16));
      uint2 ph = make_uint2(f2bf(vh.x) | ((unsigned)f2bf(vh.y) << 16),
                            f2bf(vh.z) | ((unsigned)f2bf(vh.w) << 16));
      *reinterpret_cast<uint2*>(attr_s + tid * AP + q * 4) = pa;
      *reinterpret_cast<uint2*>(h_s + tid * AP + q * 4) = ph;
    }
  } else {
#pragma unroll
    for (int q = 0; q < 8; ++q) {
      *reinterpret_cast<uint2*>(attr_s + tid * AP + q * 4) = make_uint2(0, 0);
      *reinterpret_cast<uint2*>(h_s + tid * AP + q * 4) = make_uint2(0, 0);
    }
  }

  const int lane = tid & 63;
  const int w = tid >> 6;
  const int lr = lane & 15;  // A row / B,C col within tile
  const int lg = lane >> 4;  // k-chunk / C row-group

  // B fragments for this wave's 16 col tiles (64 VGPRs), coalesced 16B loads
  bf16x8 Bf[16];
#pragma unroll
  for (int t = 0; t < 16; ++t)
    Bf[t] = *reinterpret_cast<const bf16x8*>(
        wbf + ((size_t)(w * 16 + t) * 64 + lane) * 8);
  // bias[i][o] for i = 8w+il, o = hh*16 + lr
  float biasr[8][2];
#pragma unroll
  for (int il = 0; il < 8; ++il)
#pragma unroll
    for (int hh = 0; hh < 2; ++hh)
      biasr[il][hh] = bm[(w * 8 + il) * kH + hh * 16 + lr];

  __syncthreads();

  for (int eg = 0; eg < 16; ++eg) {
    // A fragment: edges eg*16+lr, a-range lg*8..+7
    bf16x8 Af = *reinterpret_cast<const bf16x8*>(
        attr_s + (eg * 16 + lr) * AP + lg * 8);
    // h values for this lane's 4 C-rows, this wave's 8 i's (broadcast reads)
    float hf[4][8];
#pragma unroll
    for (int r = 0; r < 4; ++r) {
      bf16x8 hv = *reinterpret_cast<const bf16x8*>(
          h_s + (eg * 16 + lg * 4 + r) * AP + w * 8);
#pragma unroll
      for (int j = 0; j < 8; ++j) hf[r][j] = bf2f(hv[j]);
    }
    float ma[4][2];
#pragma unroll
    for (int r = 0; r < 4; ++r) { ma[r][0] = 0.f; ma[r][1] = 0.f; }
#pragma unroll
    for (int il = 0; il < 8; ++il) {
#pragma unroll
      for (int hh = 0; hh < 2; ++hh) {
        f32x4 c;
        c[0] = biasr[il][hh]; c[1] = biasr[il][hh];
        c[2] = biasr[il][hh]; c[3] = biasr[il][hh];
        c = __builtin_amdgcn_mfma_f32_16x16x32_bf16(Af, Bf[il * 2 + hh], c,
                                                    0, 0, 0);
#pragma unroll
        for (int r = 0; r < 4; ++r)
          ma[r][hh] = fmaf(fmaxf(c[r], 0.f), hf[r][il], ma[r][hh]);
      }
    }
#pragma unroll
    for (int r = 0; r < 4; ++r)
#pragma unroll
      for (int hh = 0; hh < 2; ++hh)
        atomicAdd(&msg_s[(eg * 16 + lg * 4 + r) * MP + hh * 16 + lr],
                  ma[r][hh]);
  }
  __syncthreads();

  if (act) {
    float* arow = agg + (size_t)dst * kH;
#pragma unroll
    for (int o4 = 0; o4 < kH / 4; ++o4) {
      float4 v = *reinterpret_cast<const float4*>(msg_s + tid * MP + o4 * 4);
      atomicAdd(arow + o4 * 4 + 0, v.x);
      atomicAdd(arow + o4 * 4 + 1, v.y);
      atomicAdd(arow + o4 * 4 + 2, v.z);
      atomicAdd(arow + o4 * 4 + 3, v.w);
    }
  }
}

// ------- conv = agg + h@rootW + rootb (in place on agg) + feature stats -------
__global__ __launch_bounds__(256) void root_stats(
    const float* __restrict__ h, const float* __restrict__ W,
    const float* __restrict__ b, float* __restrict__ conv,
    float* __restrict__ stats) {
  __shared__ float Wl[kH * kH];
  __shared__ float bl[kH];
  __shared__ float buf[256 * (kH + 1)];
  const int tid = threadIdx.x;
  for (int j = tid; j < kH * kH; j += 256) Wl[j] = W[j];
  if (tid < kH) bl[tid] = b[tid];
  __syncthreads();
  const int node = blockIdx.x * 256 + tid;
  const bool act = node < kN;
  float hr[kH];
  if (act) {
    const float4* hp = reinterpret_cast<const float4*>(h + (size_t)node * kH);
#pragma unroll
    for (int i4 = 0; i4 < kH / 4; ++i4) {
      float4 v = hp[i4];
      hr[i4 * 4 + 0] = v.x; hr[i4 * 4 + 1] = v.y;
      hr[i4 * 4 + 2] = v.z; hr[i4 * 4 + 3] = v.w;
    }
  } else {
#pragma unroll
    for (int i = 0; i < kH; ++i) hr[i] = 0.f;
  }
  float* cp = conv + (size_t)node * kH;
#pragma unroll
  for (int o = 0; o < kH; ++o) {
    float acc = 0.f;
    if (act) {
      acc = cp[o] + bl[o];
#pragma unroll
      for (int i = 0; i < kH; ++i) acc = fmaf(hr[i], Wl[i * kH + o], acc);
      cp[o] = acc;
    }
    buf[tid * (kH + 1) + o] = act ? acc : 0.f;
  }
  __syncthreads();
  if (tid < kH) {
    float s = 0.f, q = 0.f;
#pragma unroll 8
    for (int r = 0; r < 256; ++r) {
      float v = buf[r * (kH + 1) + tid];
      s += v;
      q = fmaf(v, v, q);
    }
    atomicAdd(stats + tid, s);
    atomicAdd(stats + kH + tid, q);
  }
}

// ---- hc = relu(graphnorm(conv))+h ; h = relu([h,hc] @ transW + transb) ----
__global__ __launch_bounds__(256) void norm_trans(
    const float* __restrict__ conv, const float* __restrict__ stats,
    const float* __restrict__ gw, const float* __restrict__ gb,
    const float* __restrict__ gms, const float* __restrict__ Wt,
    const float* __restrict__ tb, float* __restrict__ h) {
  __shared__ float Wl[2 * kH * kH];
  __shared__ float tbl[kH];
  __shared__ float meanl[kH], rstdl[kH], gwl[kH], gbl[kH];
  const int tid = threadIdx.x;
  for (int j = tid; j < 2 * kH * kH; j += 256) Wl[j] = Wt[j];
  if (tid < kH) {
    tbl[tid] = tb[tid];
    float m = stats[tid] * (1.f / kN);
    float q = stats[kH + tid] * (1.f / kN);
    float msv = gms[tid];
    float var = q - m * m * msv * (2.f - msv);
    meanl[tid] = msv * m;
    rstdl[tid] = rsqrtf(var + kEps);
    gwl[tid] = gw[tid];
    gbl[tid] = gb[tid];
  }
  __syncthreads();
  const int node = blockIdx.x * 256 + tid;
  if (node >= kN) return;
  float in_[2 * kH];
  const float* hp = h + (size_t)node * kH;
  const float* cp = conv + (size_t)node * kH;
#pragma unroll
  for (int i = 0; i < kH; ++i) in_[i] = hp[i];
#pragma unroll
  for (int o = 0; o < kH; ++o) {
    float v = cp[o];
    in_[kH + o] =
        fmaxf((v - meanl[o]) * rstdl[o] * gwl[o] + gbl[o], 0.f) + in_[o];
  }
  float* hw = h + (size_t)node * kH;
#pragma unroll
  for (int o = 0; o < kH; ++o) {
    float acc = tbl[o];
#pragma unroll
    for (int k = 0; k < 2 * kH; ++k) acc = fmaf(in_[k], Wl[k * kH + o], acc);
    hw[o] = fmaxf(acc, 0.f);
  }
}

// ---------- out = h @ finalW + finalb  (+ stats over kT feats) ----------
__global__ __launch_bounds__(256) void final_lin(
    const float* __restrict__ h, const float* __restrict__ W,
    const float* __restrict__ b, float* __restrict__ out,
    float* __restrict__ stats) {
  __shared__ float Wl[kH * kT];
  __shared__ float bl[kT];
  __shared__ float buf[256 * (kT + 1)];
  const int tid = threadIdx.x;
  for (int j = tid; j < kH * kT; j += 256) Wl[j] = W[j];
  if (tid < kT) bl[tid] = b[tid];
  __syncthreads();
  const int node = blockIdx.x * 256 + tid;
  const bool act = node < kN;
  float hr[kH];
  if (act) {
    const float4* hp = reinterpret_cast<const float4*>(h + (size_t)node * kH);
#pragma unroll
    for (int i4 = 0; i4 < kH / 4; ++i4) {
      float4 v = hp[i4];
      hr[i4 * 4 + 0] = v.x; hr[i4 * 4 + 1] = v.y;
      hr[i4 * 4 + 2] = v.z; hr[i4 * 4 + 3] = v.w;
    }
  } else {
#pragma unroll
    for (int i = 0; i < kH; ++i) hr[i] = 0.f;
  }
  float* op = out + (size_t)node * kT;
#pragma unroll
  for (int o = 0; o < kT; ++o) {
    float acc = 0.f;
    if (act) {
      acc = bl[o];
#pragma unroll
      for (int i = 0; i < kH; ++i) acc = fmaf(hr[i], Wl[i * kT + o], acc);
      op[o] = acc;
    }
    buf[tid * (kT + 1) + o] = act ? acc : 0.f;
  }
  __syncthreads();
  if (tid < kT) {
    float s = 0.f, q = 0.f;
#pragma unroll 8
    for (int r = 0; r < 256; ++r) {
      float v = buf[r * (kT + 1) + tid];
      s += v;
      q = fmaf(v, v, q);
    }
    atomicAdd(stats + tid, s);
    atomicAdd(stats + kT + tid, q);
  }
}

// ---------------- final graphnorm + relu (in place on out) ----------------
__global__ __launch_bounds__(256) void final_norm(
    const float* __restrict__ stats, const float* __restrict__ w,
    const float* __restrict__ b, const float* __restrict__ ms,
    float* __restrict__ out) {
  __shared__ float meanl[kT], rstdl[kT], wl2[kT], bl2[kT];
  const int tid = threadIdx.x;
  if (tid < kT) {
    float m = stats[tid] * (1.f / kN);
    float q = stats[kT + tid] * (1.f / kN);
    float msv = ms[tid];
    float var = q - m * m * msv * (2.f - msv);
    meanl[tid] = msv * m;
    rstdl[tid] = rsqrtf(var + kEps);
    wl2[tid] = w[tid];
    bl2[tid] = b[tid];
  }
  __syncthreads();
  const int node = blockIdx.x * 256 + tid;
  if (node >= kN) return;
  float* op = out + (size_t)node * kT;
#pragma unroll
  for (int o4 = 0; o4 < kT / 4; ++o4) {
    float4 v = *reinterpret_cast<const float4*>(op + o4 * 4);
    float r[4] = {v.x, v.y, v.z, v.w};
#pragma unroll
    for (int j = 0; j < 4; ++j) {
      int o = o4 * 4 + j;
      r[j] = fmaxf((r[j] - meanl[o]) * rstdl[o] * wl2[o] + bl2[o], 0.f);
    }
    *reinterpret_cast<float4*>(op + o4 * 4) =
        make_float4(r[0], r[1], r[2], r[3]);
  }
}

}  // namespace

extern "C" void kernel_launch(void* const* d_in, const int* in_sizes, int n_in,
                              void* d_out, int out_size, void* d_ws,
                              size_t ws_size, hipStream_t stream) {
  const float* x     = (const float*)d_in[0];
  const float* eattr = (const float*)d_in[1];
  const int*   eidx  = (const int*)d_in[2];
  const float* initW = (const float*)d_in[3];
  const float* initb = (const float*)d_in[4];
  const float* emW   = (const float*)d_in[5];
  const float* emb   = (const float*)d_in[6];
  const float* rW    = (const float*)d_in[7];
  const float* rb    = (const float*)d_in[8];
  const float* gnw   = (const float*)d_in[9];
  const float* gnb   = (const float*)d_in[10];
  const float* gnms  = (const float*)d_in[11];
  const float* tW    = (const float*)d_in[12];
  const float* tb    = (const float*)d_in[13];
  const float* fW    = (const float*)d_in[14];
  const float* fb    = (const float*)d_in[15];
  const float* fgw   = (const float*)d_in[16];
  const float* fgb   = (const float*)d_in[17];
  const float* fgms  = (const float*)d_in[18];
  float* out = (float*)d_out;

  float* h     = (float*)d_ws;                     // kN*kH
  float* conv  = h + (size_t)kN * kH;              // kN*kH
  float* stats = conv + (size_t)kN * kH;           // 128 floats
  unsigned short* wbf = (unsigned short*)(stats + 128);  // 3*64*64*8 bf16

  const int nodeBlocks = (kN + 255) / 256;         // 79
  const int edgeBlocks = (kE + 255) / 256;         // 313

  pack_w<<<(kL * 64 * 64 + 255) / 256, 256, 0, stream>>>(emW, wbf);
  init_proj<<<nodeBlocks, 256, 0, stream>>>(x, initW, initb, h);
  for (int l = 0; l < kL; ++l) {
    hipMemsetAsync(conv, 0, (size_t)kN * kH * sizeof(float), stream);
    edge_msg_mfma<<<edgeBlocks, 256, 0, stream>>>(
        eattr, eidx, h, wbf + (size_t)l * 64 * 64 * 8,
        emb + (size_t)l * kH * kH, conv);
    hipMemsetAsync(stats, 0, 2 * kH * sizeof(float), stream);
    root_stats<<<nodeBlocks, 256, 0, stream>>>(
        h, rW + (size_t)l * kH * kH, rb + l * kH, conv, stats);
    norm_trans<<<nodeBlocks, 256, 0, stream>>>(
        conv, stats, gnw + l * kH, gnb + l * kH, gnms + l * kH,
        tW + (size_t)l * 2 * kH * kH, tb + l * kH, h);
  }
  hipMemsetAsync(stats, 0, 2 * kT * sizeof(float), stream);
  final_lin<<<nodeBlocks, 256, 0, stream>>>(h, fW, fb, out, stats);
  final_norm<<<nodeBlocks, 256, 0, stream>>>(stats, fgw, fgb, fgms, out);
}

// Round 4
// 518.000 us; speedup vs baseline: 1.4241x; 1.4241x over previous
//
#include <hip/hip_runtime.h>

namespace {

constexpr int kN  = 20000;
constexpr int kE  = 80000;
constexpr int kIn = 64;
constexpr int kH  = 32;
constexpr int kEA = 32;
constexpr int kT  = 64;
constexpr int kL  = 3;
constexpr float kEps = 1e-5f;

typedef __attribute__((ext_vector_type(8))) short bf16x8;
typedef __attribute__((ext_vector_type(4))) float f32x4;

__device__ inline unsigned short f2bf(float f) {
  unsigned u = __builtin_bit_cast(unsigned, f);
  unsigned r = (u + 0x7fff + ((u >> 16) & 1)) >> 16;  // RNE
  return (unsigned short)r;
}
__device__ inline float bf2f(short s) {
  unsigned u = ((unsigned)(unsigned short)s) << 16;
  return __builtin_bit_cast(float, u);
}

// ---------------- edge->dst grouping: hist / scan / place ----------------
__global__ __launch_bounds__(256) void hist_dst(const int* __restrict__ ei,
                                                int* __restrict__ cnt) {
  const int e = blockIdx.x * 256 + threadIdx.x;
  if (e < kE) atomicAdd(&cnt[ei[kE + e]], 1);
}

__global__ __launch_bounds__(1024) void scan_nodes(const int* __restrict__ cnt,
                                                   int* __restrict__ off,
                                                   int* __restrict__ cursor) {
  __shared__ int buf[1024];
  __shared__ int carry_s;
  const int tid = threadIdx.x;
  if (tid == 0) carry_s = 0;
  __syncthreads();
  for (int c = 0; c < (kN + 1023) / 1024; ++c) {
    const int i = c * 1024 + tid;
    const int v = (i < kN) ? cnt[i] : 0;
    buf[tid] = v;
    __syncthreads();
    for (int s = 1; s < 1024; s <<= 1) {
      int t = 0;
      if (tid >= s) t = buf[tid - s];
      __syncthreads();
      buf[tid] += t;
      __syncthreads();
    }
    const int excl = buf[tid] - v + carry_s;
    if (i < kN) { off[i] = excl; cursor[i] = excl; }
    __syncthreads();
    if (tid == 0) carry_s += buf[1023];
    __syncthreads();
  }
}

__global__ __launch_bounds__(256) void place_edges(const int* __restrict__ ei,
                                                   int* __restrict__ cursor,
                                                   int* __restrict__ pos) {
  const int e = blockIdx.x * 256 + threadIdx.x;
  if (e < kE) pos[e] = atomicAdd(&cursor[ei[kE + e]], 1);
}

// ---- pack Wm[l] f32[32][1024] -> B-fragment-ordered bf16: frag[l][ct][lane][8]
__global__ __launch_bounds__(256) void pack_w(const float* __restrict__ emW,
                                              unsigned short* __restrict__ wbf) {
  const int idx = blockIdx.x * 256 + threadIdx.x;
  if (idx >= kL * 64 * 64) return;
  const int lane = idx & 63, ct = (idx >> 6) & 63, l = idx >> 12;
  const int k0 = (lane >> 4) * 8, c = ct * 16 + (lane & 15);
  const float* W = emW + (size_t)l * kEA * kH * kH;
  unsigned out[4];
#pragma unroll
  for (int p = 0; p < 4; ++p) {
    unsigned lo = f2bf(W[(size_t)(k0 + 2 * p) * (kH * kH) + c]);
    unsigned hi = f2bf(W[(size_t)(k0 + 2 * p + 1) * (kH * kH) + c]);
    out[p] = lo | (hi << 16);
  }
  *reinterpret_cast<uint4*>(wbf + (size_t)idx * 8) =
      make_uint4(out[0], out[1], out[2], out[3]);
}

// ---------------- h = x @ initW + initb ----------------
__global__ __launch_bounds__(256) void init_proj(
    const float* __restrict__ x, const float* __restrict__ W,
    const float* __restrict__ b, float* __restrict__ h) {
  __shared__ float Wl[kIn * kH];
  __shared__ float bl[kH];
  const int tid = threadIdx.x;
  for (int j = tid; j < kIn * kH; j += 256) Wl[j] = W[j];
  if (tid < kH) bl[tid] = b[tid];
  __syncthreads();
  const int node = blockIdx.x * 256 + tid;
  if (node >= kN) return;
  float xr[kIn];
  const float4* xp = reinterpret_cast<const float4*>(x + (size_t)node * kIn);
#pragma unroll
  for (int k4 = 0; k4 < kIn / 4; ++k4) {
    float4 v = xp[k4];
    xr[k4 * 4 + 0] = v.x; xr[k4 * 4 + 1] = v.y;
    xr[k4 * 4 + 2] = v.z; xr[k4 * 4 + 3] = v.w;
  }
  float* hp = h + (size_t)node * kH;
#pragma unroll
  for (int o = 0; o < kH; ++o) {
    float acc = bl[o];
#pragma unroll
    for (int k = 0; k < kIn; ++k) acc = fmaf(xr[k], Wl[k * kH + o], acc);
    hp[o] = acc;
  }
}

// ------------- MFMA edge MLP + message -> msg_buf[pos[e]] -------------
constexpr int AP = 40;  // attr/h LDS row pitch in ushorts (80 B)
constexpr int MP = 36;  // msg LDS row pitch in f32 (144 B)
__global__ __launch_bounds__(256) void edge_msg_mfma(
    const float* __restrict__ attr, const int* __restrict__ ei,
    const int* __restrict__ pos, const float* __restrict__ h,
    const unsigned short* __restrict__ wbf, const float* __restrict__ bm,
    float* __restrict__ msg_buf) {
  __shared__ unsigned short attr_s[256 * AP];  // 20 KB bf16
  __shared__ unsigned short h_s[256 * AP];     // 20 KB bf16
  __shared__ float msg_s[256 * MP];            // 36 KB f32
  const int tid = threadIdx.x;
  const int e = blockIdx.x * 256 + tid;
  const bool act = e < kE;

  for (int j = tid; j < 256 * MP; j += 256) msg_s[j] = 0.f;

  if (act) {
    const int src = ei[e];
    const float4* ap = reinterpret_cast<const float4*>(attr + (size_t)e * kEA);
    const float4* hp = reinterpret_cast<const float4*>(h + (size_t)src * kH);
#pragma unroll
    for (int q = 0; q < 8; ++q) {
      float4 va = ap[q];
      float4 vh = hp[q];
      uint2 pa = make_uint2(f2bf(va.x) | ((unsigned)f2bf(va.y) << 16),
                            f2bf(va.z) | ((unsigned)f2bf(va.w) << 16));
      uint2 ph = make_uint2(f2bf(vh.x) | ((unsigned)f2bf(vh.y) << 16),
                            f2bf(vh.z) | ((unsigned)f2bf(vh.w) << 16));
      *reinterpret_cast<uint2*>(attr_s + tid * AP + q * 4) = pa;
      *reinterpret_cast<uint2*>(h_s + tid * AP + q * 4) = ph;
    }
  } else {
#pragma unroll
    for (int q = 0; q < 8; ++q) {
      *reinterpret_cast<uint2*>(attr_s + tid * AP + q * 4) = make_uint2(0, 0);
      *reinterpret_cast<uint2*>(h_s + tid * AP + q * 4) = make_uint2(0, 0);
    }
  }

  const int lane = tid & 63;
  const int w = tid >> 6;
  const int lr = lane & 15;  // A row / B,C col within tile
  const int lg = lane >> 4;  // k-chunk / C row-group

  bf16x8 Bf[16];
#pragma unroll
  for (int t = 0; t < 16; ++t)
    Bf[t] = *reinterpret_cast<const bf16x8*>(
        wbf + ((size_t)(w * 16 + t) * 64 + lane) * 8);
  float biasr[8][2];
#pragma unroll
  for (int il = 0; il < 8; ++il)
#pragma unroll
    for (int hh = 0; hh < 2; ++hh)
      biasr[il][hh] = bm[(w * 8 + il) * kH + hh * 16 + lr];

  __syncthreads();

  for (int eg = 0; eg < 16; ++eg) {
    bf16x8 Af = *reinterpret_cast<const bf16x8*>(
        attr_s + (eg * 16 + lr) * AP + lg * 8);
    float hf[4][8];
#pragma unroll
    for (int r = 0; r < 4; ++r) {
      bf16x8 hv = *reinterpret_cast<const bf16x8*>(
          h_s + (eg * 16 + lg * 4 + r) * AP + w * 8);
#pragma unroll
      for (int j = 0; j < 8; ++j) hf[r][j] = bf2f(hv[j]);
    }
    float ma[4][2];
#pragma unroll
    for (int r = 0; r < 4; ++r) { ma[r][0] = 0.f; ma[r][1] = 0.f; }
#pragma unroll
    for (int il = 0; il < 8; ++il) {
#pragma unroll
      for (int hh = 0; hh < 2; ++hh) {
        f32x4 c;
        c[0] = biasr[il][hh]; c[1] = biasr[il][hh];
        c[2] = biasr[il][hh]; c[3] = biasr[il][hh];
        c = __builtin_amdgcn_mfma_f32_16x16x32_bf16(Af, Bf[il * 2 + hh], c,
                                                    0, 0, 0);
#pragma unroll
        for (int r = 0; r < 4; ++r)
          ma[r][hh] = fmaf(fmaxf(c[r], 0.f), hf[r][il], ma[r][hh]);
      }
    }
#pragma unroll
    for (int r = 0; r < 4; ++r)
#pragma unroll
      for (int hh = 0; hh < 2; ++hh)
        atomicAdd(&msg_s[(eg * 16 + lg * 4 + r) * MP + hh * 16 + lr],
                  ma[r][hh]);
  }
  __syncthreads();

  if (act) {
    float* mrow = msg_buf + (size_t)pos[e] * kH;
#pragma unroll
    for (int o4 = 0; o4 < kH / 4; ++o4)
      *reinterpret_cast<float4*>(mrow + o4 * 4) =
          *reinterpret_cast<const float4*>(msg_s + tid * MP + o4 * 4);
  }
}

// ------- wave-per-node segmented sum: conv[n] = sum of msg rows -------
__global__ __launch_bounds__(256) void agg_nodes(
    const float* __restrict__ msg, const int* __restrict__ off,
    const int* __restrict__ cnt, float* __restrict__ conv) {
  const int wid = (blockIdx.x * 256 + threadIdx.x) >> 6;
  const int lane = threadIdx.x & 63;
  const int col = lane & 31, half = lane >> 5;
  if (wid >= kN) return;
  const int s = off[wid], n = cnt[wid];
  float acc = 0.f;
  for (int j = half; j < n; j += 2)
    acc += msg[(size_t)(s + j) * kH + col];
  acc += __shfl_xor(acc, 32);
  if (half == 0) conv[(size_t)wid * kH + col] = acc;
}

// ------- conv += h@rootW + rootb (in place) + feature stats -------
__global__ __launch_bounds__(256) void root_stats(
    const float* __restrict__ h, const float* __restrict__ W,
    const float* __restrict__ b, float* __restrict__ conv,
    float* __restrict__ stats) {
  __shared__ float Wl[kH * kH];
  __shared__ float bl[kH];
  __shared__ float buf[256 * (kH + 1)];
  const int tid = threadIdx.x;
  for (int j = tid; j < kH * kH; j += 256) Wl[j] = W[j];
  if (tid < kH) bl[tid] = b[tid];
  __syncthreads();
  const int node = blockIdx.x * 256 + tid;
  const bool act = node < kN;
  float hr[kH];
  if (act) {
    const float4* hp = reinterpret_cast<const float4*>(h + (size_t)node * kH);
#pragma unroll
    for (int i4 = 0; i4 < kH / 4; ++i4) {
      float4 v = hp[i4];
      hr[i4 * 4 + 0] = v.x; hr[i4 * 4 + 1] = v.y;
      hr[i4 * 4 + 2] = v.z; hr[i4 * 4 + 3] = v.w;
    }
  } else {
#pragma unroll
    for (int i = 0; i < kH; ++i) hr[i] = 0.f;
  }
  float* cp = conv + (size_t)node * kH;
#pragma unroll
  for (int o = 0; o < kH; ++o) {
    float acc = 0.f;
    if (act) {
      acc = cp[o] + bl[o];
#pragma unroll
      for (int i = 0; i < kH; ++i) acc = fmaf(hr[i], Wl[i * kH + o], acc);
      cp[o] = acc;
    }
    buf[tid * (kH + 1) + o] = act ? acc : 0.f;
  }
  __syncthreads();
  if (tid < kH) {
    float s = 0.f, q = 0.f;
#pragma unroll 8
    for (int r = 0; r < 256; ++r) {
      float v = buf[r * (kH + 1) + tid];
      s += v;
      q = fmaf(v, v, q);
    }
    atomicAdd(stats + tid, s);
    atomicAdd(stats + kH + tid, q);
  }
}

// ---- hc = relu(graphnorm(conv))+h ; h = relu([h,hc] @ transW + transb) ----
__global__ __launch_bounds__(256) void norm_trans(
    const float* __restrict__ conv, const float* __restrict__ stats,
    const float* __restrict__ gw, const float* __restrict__ gb,
    const float* __restrict__ gms, const float* __restrict__ Wt,
    const float* __restrict__ tb, float* __restrict__ h) {
  __shared__ float Wl[2 * kH * kH];
  __shared__ float tbl[kH];
  __shared__ float meanl[kH], rstdl[kH], gwl[kH], gbl[kH];
  const int tid = threadIdx.x;
  for (int j = tid; j < 2 * kH * kH; j += 256) Wl[j] = Wt[j];
  if (tid < kH) {
    tbl[tid] = tb[tid];
    float m = stats[tid] * (1.f / kN);
    float q = stats[kH + tid] * (1.f / kN);
    float msv = gms[tid];
    float var = q - m * m * msv * (2.f - msv);
    meanl[tid] = msv * m;
    rstdl[tid] = rsqrtf(var + kEps);
    gwl[tid] = gw[tid];
    gbl[tid] = gb[tid];
  }
  __syncthreads();
  const int node = blockIdx.x * 256 + tid;
  if (node >= kN) return;
  float in_[2 * kH];
  const float* hp = h + (size_t)node * kH;
  const float* cp = conv + (size_t)node * kH;
#pragma unroll
  for (int i = 0; i < kH; ++i) in_[i] = hp[i];
#pragma unroll
  for (int o = 0; o < kH; ++o) {
    float v = cp[o];
    in_[kH + o] =
        fmaxf((v - meanl[o]) * rstdl[o] * gwl[o] + gbl[o], 0.f) + in_[o];
  }
  float* hw = h + (size_t)node * kH;
#pragma unroll
  for (int o = 0; o < kH; ++o) {
    float acc = tbl[o];
#pragma unroll
    for (int k = 0; k < 2 * kH; ++k) acc = fmaf(in_[k], Wl[k * kH + o], acc);
    hw[o] = fmaxf(acc, 0.f);
  }
}

// ---------- out = h @ finalW + finalb  (+ stats over kT feats) ----------
__global__ __launch_bounds__(256) void final_lin(
    const float* __restrict__ h, const float* __restrict__ W,
    const float* __restrict__ b, float* __restrict__ out,
    float* __restrict__ stats) {
  __shared__ float Wl[kH * kT];
  __shared__ float bl[kT];
  __shared__ float buf[256 * (kT + 1)];
  const int tid = threadIdx.x;
  for (int j = tid; j < kH * kT; j += 256) Wl[j] = W[j];
  if (tid < kT) bl[tid] = b[tid];
  __syncthreads();
  const int node = blockIdx.x * 256 + tid;
  const bool act = node < kN;
  float hr[kH];
  if (act) {
    const float4* hp = reinterpret_cast<const float4*>(h + (size_t)node * kH);
#pragma unroll
    for (int i4 = 0; i4 < kH / 4; ++i4) {
      float4 v = hp[i4];
      hr[i4 * 4 + 0] = v.x; hr[i4 * 4 + 1] = v.y;
      hr[i4 * 4 + 2] = v.z; hr[i4 * 4 + 3] = v.w;
    }
  } else {
#pragma unroll
    for (int i = 0; i < kH; ++i) hr[i] = 0.f;
  }
  float* op = out + (size_t)node * kT;
#pragma unroll
  for (int o = 0; o < kT; ++o) {
    float acc = 0.f;
    if (act) {
      acc = bl[o];
#pragma unroll
      for (int i = 0; i < kH; ++i) acc = fmaf(hr[i], Wl[i * kT + o], acc);
      op[o] = acc;
    }
    buf[tid * (kT + 1) + o] = act ? acc : 0.f;
  }
  __syncthreads();
  if (tid < kT) {
    float s = 0.f, q = 0.f;
#pragma unroll 8
    for (int r = 0; r < 256; ++r) {
      float v = buf[r * (kT + 1) + tid];
      s += v;
      q = fmaf(v, v, q);
    }
    atomicAdd(stats + tid, s);
    atomicAdd(stats + kT + tid, q);
  }
}

// ---------------- final graphnorm + relu (in place on out) ----------------
__global__ __launch_bounds__(256) void final_norm(
    const float* __restrict__ stats, const float* __restrict__ w,
    const float* __restrict__ b, const float* __restrict__ ms,
    float* __restrict__ out) {
  __shared__ float meanl[kT], rstdl[kT], wl2[kT], bl2[kT];
  const int tid = threadIdx.x;
  if (tid < kT) {
    float m = stats[tid] * (1.f / kN);
    float q = stats[kT + tid] * (1.f / kN);
    float msv = ms[tid];
    float var = q - m * m * msv * (2.f - msv);
    meanl[tid] = msv * m;
    rstdl[tid] = rsqrtf(var + kEps);
    wl2[tid] = w[tid];
    bl2[tid] = b[tid];
  }
  __syncthreads();
  const int node = blockIdx.x * 256 + tid;
  if (node >= kN) return;
  float* op = out + (size_t)node * kT;
#pragma unroll
  for (int o4 = 0; o4 < kT / 4; ++o4) {
    float4 v = *reinterpret_cast<const float4*>(op + o4 * 4);
    float r[4] = {v.x, v.y, v.z, v.w};
#pragma unroll
    for (int j = 0; j < 4; ++j) {
      int o = o4 * 4 + j;
      r[j] = fmaxf((r[j] - meanl[o]) * rstdl[o] * wl2[o] + bl2[o], 0.f);
    }
    *reinterpret_cast<float4*>(op + o4 * 4) =
        make_float4(r[0], r[1], r[2], r[3]);
  }
}

}  // namespace

extern "C" void kernel_launch(void* const* d_in, const int* in_sizes, int n_in,
                              void* d_out, int out_size, void* d_ws,
                              size_t ws_size, hipStream_t stream) {
  const float* x     = (const float*)d_in[0];
  const float* eattr = (const float*)d_in[1];
  const int*   eidx  = (const int*)d_in[2];
  const float* initW = (const float*)d_in[3];
  const float* initb = (const float*)d_in[4];
  const float* emW   = (const float*)d_in[5];
  const float* emb   = (const float*)d_in[6];
  const float* rW    = (const float*)d_in[7];
  const float* rb    = (const float*)d_in[8];
  const float* gnw   = (const float*)d_in[9];
  const float* gnb   = (const float*)d_in[10];
  const float* gnms  = (const float*)d_in[11];
  const float* tW    = (const float*)d_in[12];
  const float* tb    = (const float*)d_in[13];
  const float* fW    = (const float*)d_in[14];
  const float* fb    = (const float*)d_in[15];
  const float* fgw   = (const float*)d_in[16];
  const float* fgb   = (const float*)d_in[17];
  const float* fgms  = (const float*)d_in[18];
  float* out = (float*)d_out;

  // workspace layout
  float* h     = (float*)d_ws;                       // kN*kH f32
  float* conv  = h + (size_t)kN * kH;                // kN*kH f32
  float* stats = conv + (size_t)kN * kH;             // 128 f32
  float* msg   = stats + 128;                        // kE*kH f32
  unsigned short* wbf = (unsigned short*)(msg + (size_t)kE * kH);  // 196 KB
  int* cnt    = (int*)(wbf + (size_t)kL * 64 * 64 * 8);  // kN
  int* off    = cnt + kN;                            // kN
  int* cursor = off + kN;                            // kN
  int* pos    = cursor + kN;                         // kE

  const int nodeBlocks = (kN + 255) / 256;           // 79
  const int edgeBlocks = (kE + 255) / 256;           // 313
  const int aggBlocks  = (kN * 64 + 255) / 256;      // 5000 (wave per node)

  // one-time per call: group edges by dst
  hipMemsetAsync(cnt, 0, kN * sizeof(int), stream);
  hist_dst<<<edgeBlocks, 256, 0, stream>>>(eidx, cnt);
  scan_nodes<<<1, 1024, 0, stream>>>(cnt, off, cursor);
  place_edges<<<edgeBlocks, 256, 0, stream>>>(eidx, cursor, pos);

  pack_w<<<(kL * 64 * 64 + 255) / 256, 256, 0, stream>>>(emW, wbf);
  init_proj<<<nodeBlocks, 256, 0, stream>>>(x, initW, initb, h);
  for (int l = 0; l < kL; ++l) {
    edge_msg_mfma<<<edgeBlocks, 256, 0, stream>>>(
        eattr, eidx, pos, h, wbf + (size_t)l * 64 * 64 * 8,
        emb + (size_t)l * kH * kH, msg);
    agg_nodes<<<aggBlocks, 256, 0, stream>>>(msg, off, cnt, conv);
    hipMemsetAsync(stats, 0, 2 * kH * sizeof(float), stream);
    root_stats<<<nodeBlocks, 256, 0, stream>>>(
        h, rW + (size_t)l * kH * kH, rb + l * kH, conv, stats);
    norm_trans<<<nodeBlocks, 256, 0, stream>>>(
        conv, stats, gnw + l * kH, gnb + l * kH, gnms + l * kH,
        tW + (size_t)l * 2 * kH * kH, tb + l * kH, h);
  }
  hipMemsetAsync(stats, 0, 2 * kT * sizeof(float), stream);
  final_lin<<<nodeBlocks, 256, 0, stream>>>(h, fW, fb, out, stats);
  final_norm<<<nodeBlocks, 256, 0, stream>>>(stats, fgw, fgb, fgms, out);
}

// Round 6
// 409.794 us; speedup vs baseline: 1.8002x; 1.2640x over previous
//
#include <hip/hip_runtime.h>

namespace {

constexpr int kN  = 20000;
constexpr int kE  = 80000;
constexpr int kIn = 64;
constexpr int kH  = 32;
constexpr int kEA = 32;
constexpr int kT  = 64;
constexpr int kL  = 3;
constexpr float kEps = 1e-5f;

typedef __attribute__((ext_vector_type(8))) short bf16x8;
typedef __attribute__((ext_vector_type(4))) float f32x4;

__device__ inline unsigned short f2bf(float f) {
  unsigned u = __builtin_bit_cast(unsigned, f);
  unsigned r = (u + 0x7fff + ((u >> 16) & 1)) >> 16;  // RNE
  return (unsigned short)r;
}
__device__ inline float bf2f(short s) {
  unsigned u = ((unsigned)(unsigned short)s) << 16;
  return __builtin_bit_cast(float, u);
}

// ---------------- edge->dst grouping: hist / scan / place ----------------
__global__ __launch_bounds__(256) void hist_dst(const int* __restrict__ ei,
                                                int* __restrict__ cnt) {
  const int e = blockIdx.x * 256 + threadIdx.x;
  if (e < kE) atomicAdd(&cnt[ei[kE + e]], 1);
}

__global__ __launch_bounds__(1024) void scan_nodes(const int* __restrict__ cnt,
                                                   int* __restrict__ off,
                                                   int* __restrict__ cursor) {
  __shared__ int buf[1024];
  __shared__ int carry_s;
  const int tid = threadIdx.x;
  if (tid == 0) carry_s = 0;
  __syncthreads();
  for (int c = 0; c < (kN + 1023) / 1024; ++c) {
    const int i = c * 1024 + tid;
    const int v = (i < kN) ? cnt[i] : 0;
    buf[tid] = v;
    __syncthreads();
    for (int s = 1; s < 1024; s <<= 1) {
      int t = 0;
      if (tid >= s) t = buf[tid - s];
      __syncthreads();
      buf[tid] += t;
      __syncthreads();
    }
    const int excl = buf[tid] - v + carry_s;
    if (i < kN) { off[i] = excl; cursor[i] = excl; }
    __syncthreads();
    if (tid == 0) carry_s += buf[1023];
    __syncthreads();
  }
}

__global__ __launch_bounds__(256) void place_edges(const int* __restrict__ ei,
                                                   int* __restrict__ cursor,
                                                   int* __restrict__ pos) {
  const int e = blockIdx.x * 256 + threadIdx.x;
  if (e < kE) pos[e] = atomicAdd(&cursor[ei[kE + e]], 1);
}

// ---- pack Wm[l] f32[32][1024] -> B-fragment-ordered bf16: frag[l][ct][lane][8]
__global__ __launch_bounds__(256) void pack_w(const float* __restrict__ emW,
                                              unsigned short* __restrict__ wbf) {
  const int idx = blockIdx.x * 256 + threadIdx.x;
  if (idx >= kL * 64 * 64) return;
  const int lane = idx & 63, ct = (idx >> 6) & 63, l = idx >> 12;
  const int k0 = (lane >> 4) * 8, c = ct * 16 + (lane & 15);
  const float* W = emW + (size_t)l * kEA * kH * kH;
  unsigned out[4];
#pragma unroll
  for (int p = 0; p < 4; ++p) {
    unsigned lo = f2bf(W[(size_t)(k0 + 2 * p) * (kH * kH) + c]);
    unsigned hi = f2bf(W[(size_t)(k0 + 2 * p + 1) * (kH * kH) + c]);
    out[p] = lo | (hi << 16);
  }
  *reinterpret_cast<uint4*>(wbf + (size_t)idx * 8) =
      make_uint4(out[0], out[1], out[2], out[3]);
}

// ---------------- h = x @ initW + initb (round-4 known-good) ----------------
__global__ __launch_bounds__(256) void init_proj(
    const float* __restrict__ x, const float* __restrict__ W,
    const float* __restrict__ b, float* __restrict__ h) {
  __shared__ float Wl[kIn * kH];
  __shared__ float bl[kH];
  const int tid = threadIdx.x;
  for (int j = tid; j < kIn * kH; j += 256) Wl[j] = W[j];
  if (tid < kH) bl[tid] = b[tid];
  __syncthreads();
  const int node = blockIdx.x * 256 + tid;
  if (node >= kN) return;
  float xr[kIn];
  const float4* xp = reinterpret_cast<const float4*>(x + (size_t)node * kIn);
#pragma unroll
  for (int k4 = 0; k4 < kIn / 4; ++k4) {
    float4 v = xp[k4];
    xr[k4 * 4 + 0] = v.x; xr[k4 * 4 + 1] = v.y;
    xr[k4 * 4 + 2] = v.z; xr[k4 * 4 + 3] = v.w;
  }
  float* hp = h + (size_t)node * kH;
#pragma unroll
  for (int o = 0; o < kH; ++o) {
    float acc = bl[o];
#pragma unroll
    for (int k = 0; k < kIn; ++k) acc = fmaf(xr[k], Wl[k * kH + o], acc);
    hp[o] = acc;
  }
}

// ------------- MFMA edge MLP + message -> msg_buf[pos[e]] (EB=64) -------------
constexpr int EB = 64;  // edges per block (kE = 1250*64 exactly)
constexpr int AP = 40;  // attr/h LDS row pitch in ushorts (80 B)
constexpr int MP = 36;  // msg LDS row pitch in f32 (144 B)
__global__ __launch_bounds__(256) void edge_msg_mfma(
    const float* __restrict__ attr, const int* __restrict__ ei,
    const int* __restrict__ pos, const float* __restrict__ h,
    const unsigned short* __restrict__ wbf, const float* __restrict__ bm,
    float* __restrict__ msg_buf) {
  __shared__ unsigned short attr_s[EB * AP];  // 5 KB
  __shared__ unsigned short h_s[EB * AP];     // 5 KB
  __shared__ float msg_s[EB * MP];            // 9 KB
  const int tid = threadIdx.x;
  const int base = blockIdx.x * EB;

  for (int j = tid; j < EB * MP; j += 256) msg_s[j] = 0.f;

  // stage: 4 threads per edge, 8 attr + 8 h floats each
  {
    const int el = tid >> 2, p = tid & 3;
    const int e = base + el;
    const int src = ei[e];
    const float4* ap =
        reinterpret_cast<const float4*>(attr + (size_t)e * kEA) + p * 2;
    const float4* hp =
        reinterpret_cast<const float4*>(h + (size_t)src * kH) + p * 2;
    float4 a0 = ap[0], a1 = ap[1];
    float4 h0 = hp[0], h1 = hp[1];
    uint2 pa0 = make_uint2(f2bf(a0.x) | ((unsigned)f2bf(a0.y) << 16),
                           f2bf(a0.z) | ((unsigned)f2bf(a0.w) << 16));
    uint2 pa1 = make_uint2(f2bf(a1.x) | ((unsigned)f2bf(a1.y) << 16),
                           f2bf(a1.z) | ((unsigned)f2bf(a1.w) << 16));
    uint2 ph0 = make_uint2(f2bf(h0.x) | ((unsigned)f2bf(h0.y) << 16),
                           f2bf(h0.z) | ((unsigned)f2bf(h0.w) << 16));
    uint2 ph1 = make_uint2(f2bf(h1.x) | ((unsigned)f2bf(h1.y) << 16),
                           f2bf(h1.z) | ((unsigned)f2bf(h1.w) << 16));
    *reinterpret_cast<uint2*>(attr_s + el * AP + p * 8) = pa0;
    *reinterpret_cast<uint2*>(attr_s + el * AP + p * 8 + 4) = pa1;
    *reinterpret_cast<uint2*>(h_s + el * AP + p * 8) = ph0;
    *reinterpret_cast<uint2*>(h_s + el * AP + p * 8 + 4) = ph1;
  }

  const int lane = tid & 63;
  const int w = tid >> 6;
  const int lr = lane & 15;  // A row / B,C col within tile
  const int lg = lane >> 4;  // k-chunk / C row-group

  bf16x8 Bf[16];
#pragma unroll
  for (int t = 0; t < 16; ++t)
    Bf[t] = *reinterpret_cast<const bf16x8*>(
        wbf + ((size_t)(w * 16 + t) * 64 + lane) * 8);
  float biasr[8][2];
#pragma unroll
  for (int il = 0; il < 8; ++il)
#pragma unroll
    for (int hh = 0; hh < 2; ++hh)
      biasr[il][hh] = bm[(w * 8 + il) * kH + hh * 16 + lr];

  int mypos = 0;
  if (tid < EB) mypos = pos[base + tid];

  __syncthreads();

#pragma unroll
  for (int eg = 0; eg < EB / 16; ++eg) {
    bf16x8 Af = *reinterpret_cast<const bf16x8*>(
        attr_s + (eg * 16 + lr) * AP + lg * 8);
    float hf[4][8];
#pragma unroll
    for (int r = 0; r < 4; ++r) {
      bf16x8 hv = *reinterpret_cast<const bf16x8*>(
          h_s + (eg * 16 + lg * 4 + r) * AP + w * 8);
#pragma unroll
      for (int j = 0; j < 8; ++j) hf[r][j] = bf2f(hv[j]);
    }
    float ma[4][2];
#pragma unroll
    for (int r = 0; r < 4; ++r) { ma[r][0] = 0.f; ma[r][1] = 0.f; }
#pragma unroll
    for (int il = 0; il < 8; ++il) {
#pragma unroll
      for (int hh = 0; hh < 2; ++hh) {
        f32x4 c;
        c[0] = biasr[il][hh]; c[1] = biasr[il][hh];
        c[2] = biasr[il][hh]; c[3] = biasr[il][hh];
        c = __builtin_amdgcn_mfma_f32_16x16x32_bf16(Af, Bf[il * 2 + hh], c,
                                                    0, 0, 0);
#pragma unroll
        for (int r = 0; r < 4; ++r)
          ma[r][hh] = fmaf(fmaxf(c[r], 0.f), hf[r][il], ma[r][hh]);
      }
    }
#pragma unroll
    for (int r = 0; r < 4; ++r)
#pragma unroll
      for (int hh = 0; hh < 2; ++hh)
        atomicAdd(&msg_s[(eg * 16 + lg * 4 + r) * MP + hh * 16 + lr],
                  ma[r][hh]);
  }
  __syncthreads();

  if (tid < EB) {
    float* mrow = msg_buf + (size_t)mypos * kH;
#pragma unroll
    for (int o4 = 0; o4 < kH / 4; ++o4)
      *reinterpret_cast<float4*>(mrow + o4 * 4) =
          *reinterpret_cast<const float4*>(msg_s + tid * MP + o4 * 4);
  }
}

// ------- wave-per-node segmented sum (round-4 known-good) -------
__global__ __launch_bounds__(256) void agg_nodes(
    const float* __restrict__ msg, const int* __restrict__ off,
    const int* __restrict__ cnt, float* __restrict__ conv) {
  const int wid = (blockIdx.x * 256 + threadIdx.x) >> 6;
  const int lane = threadIdx.x & 63;
  const int col = lane & 31, half = lane >> 5;
  if (wid >= kN) return;
  const int s = off[wid], n = cnt[wid];
  float acc = 0.f;
  for (int j = half; j < n; j += 2)
    acc += msg[(size_t)(s + j) * kH + col];
  acc += __shfl_xor(acc, 32);
  if (half == 0) conv[(size_t)wid * kH + col] = acc;
}

// ------- conv += h@rootW + rootb + feature stats (round-4 known-good) -------
__global__ __launch_bounds__(256) void root_stats(
    const float* __restrict__ h, const float* __restrict__ W,
    const float* __restrict__ b, float* __restrict__ conv,
    float* __restrict__ stats) {
  __shared__ float Wl[kH * kH];
  __shared__ float bl[kH];
  __shared__ float buf[256 * (kH + 1)];
  const int tid = threadIdx.x;
  for (int j = tid; j < kH * kH; j += 256) Wl[j] = W[j];
  if (tid < kH) bl[tid] = b[tid];
  __syncthreads();
  const int node = blockIdx.x * 256 + tid;
  const bool act = node < kN;
  float hr[kH];
  if (act) {
    const float4* hp = reinterpret_cast<const float4*>(h + (size_t)node * kH);
#pragma unroll
    for (int i4 = 0; i4 < kH / 4; ++i4) {
      float4 v = hp[i4];
      hr[i4 * 4 + 0] = v.x; hr[i4 * 4 + 1] = v.y;
      hr[i4 * 4 + 2] = v.z; hr[i4 * 4 + 3] = v.w;
    }
  } else {
#pragma unroll
    for (int i = 0; i < kH; ++i) hr[i] = 0.f;
  }
  float* cp = conv + (size_t)node * kH;
#pragma unroll
  for (int o = 0; o < kH; ++o) {
    float acc = 0.f;
    if (act) {
      acc = cp[o] + bl[o];
#pragma unroll
      for (int i = 0; i < kH; ++i) acc = fmaf(hr[i], Wl[i * kH + o], acc);
      cp[o] = acc;
    }
    buf[tid * (kH + 1) + o] = act ? acc : 0.f;
  }
  __syncthreads();
  if (tid < kH) {
    float s = 0.f, q = 0.f;
#pragma unroll 8
    for (int r = 0; r < 256; ++r) {
      float v = buf[r * (kH + 1) + tid];
      s += v;
      q = fmaf(v, v, q);
    }
    atomicAdd(stats + tid, s);
    atomicAdd(stats + kH + tid, q);
  }
}

// ---- hc/trans (round-4 known-good) ----
__global__ __launch_bounds__(256) void norm_trans(
    const float* __restrict__ conv, const float* __restrict__ stats,
    const float* __restrict__ gw, const float* __restrict__ gb,
    const float* __restrict__ gms, const float* __restrict__ Wt,
    const float* __restrict__ tb, float* __restrict__ h) {
  __shared__ float Wl[2 * kH * kH];
  __shared__ float tbl[kH];
  __shared__ float meanl[kH], rstdl[kH], gwl[kH], gbl[kH];
  const int tid = threadIdx.x;
  for (int j = tid; j < 2 * kH * kH; j += 256) Wl[j] = Wt[j];
  if (tid < kH) {
    tbl[tid] = tb[tid];
    float m = stats[tid] * (1.f / kN);
    float q = stats[kH + tid] * (1.f / kN);
    float msv = gms[tid];
    float var = q - m * m * msv * (2.f - msv);
    meanl[tid] = msv * m;
    rstdl[tid] = rsqrtf(var + kEps);
    gwl[tid] = gw[tid];
    gbl[tid] = gb[tid];
  }
  __syncthreads();
  const int node = blockIdx.x * 256 + tid;
  if (node >= kN) return;
  float in_[2 * kH];
  const float* hp = h + (size_t)node * kH;
  const float* cp = conv + (size_t)node * kH;
#pragma unroll
  for (int i = 0; i < kH; ++i) in_[i] = hp[i];
#pragma unroll
  for (int o = 0; o < kH; ++o) {
    float v = cp[o];
    in_[kH + o] =
        fmaxf((v - meanl[o]) * rstdl[o] * gwl[o] + gbl[o], 0.f) + in_[o];
  }
  float* hw = h + (size_t)node * kH;
#pragma unroll
  for (int o = 0; o < kH; ++o) {
    float acc = tbl[o];
#pragma unroll
    for (int k = 0; k < 2 * kH; ++k) acc = fmaf(in_[k], Wl[k * kH + o], acc);
    hw[o] = fmaxf(acc, 0.f);
  }
}

// ---------- final linear + stats (round-4 known-good) ----------
__global__ __launch_bounds__(256) void final_lin(
    const float* __restrict__ h, const float* __restrict__ W,
    const float* __restrict__ b, float* __restrict__ out,
    float* __restrict__ stats) {
  __shared__ float Wl[kH * kT];
  __shared__ float bl[kT];
  __shared__ float buf[256 * (kT + 1)];
  const int tid = threadIdx.x;
  for (int j = tid; j < kH * kT; j += 256) Wl[j] = W[j];
  if (tid < kT) bl[tid] = b[tid];
  __syncthreads();
  const int node = blockIdx.x * 256 + tid;
  const bool act = node < kN;
  float hr[kH];
  if (act) {
    const float4* hp = reinterpret_cast<const float4*>(h + (size_t)node * kH);
#pragma unroll
    for (int i4 = 0; i4 < kH / 4; ++i4) {
      float4 v = hp[i4];
      hr[i4 * 4 + 0] = v.x; hr[i4 * 4 + 1] = v.y;
      hr[i4 * 4 + 2] = v.z; hr[i4 * 4 + 3] = v.w;
    }
  } else {
#pragma unroll
    for (int i = 0; i < kH; ++i) hr[i] = 0.f;
  }
  float* op = out + (size_t)node * kT;
#pragma unroll
  for (int o = 0; o < kT; ++o) {
    float acc = 0.f;
    if (act) {
      acc = bl[o];
#pragma unroll
      for (int i = 0; i < kH; ++i) acc = fmaf(hr[i], Wl[i * kT + o], acc);
      op[o] = acc;
    }
    buf[tid * (kT + 1) + o] = act ? acc : 0.f;
  }
  __syncthreads();
  if (tid < kT) {
    float s = 0.f, q = 0.f;
#pragma unroll 8
    for (int r = 0; r < 256; ++r) {
      float v = buf[r * (kT + 1) + tid];
      s += v;
      q = fmaf(v, v, q);
    }
    atomicAdd(stats + tid, s);
    atomicAdd(stats + kT + tid, q);
  }
}

// ---------------- final graphnorm + relu (round-4 known-good) ----------------
__global__ __launch_bounds__(256) void final_norm(
    const float* __restrict__ stats, const float* __restrict__ w,
    const float* __restrict__ b, const float* __restrict__ ms,
    float* __restrict__ out) {
  __shared__ float meanl[kT], rstdl[kT], wl2[kT], bl2[kT];
  const int tid = threadIdx.x;
  if (tid < kT) {
    float m = stats[tid] * (1.f / kN);
    float q = stats[kT + tid] * (1.f / kN);
    float msv = ms[tid];
    float var = q - m * m * msv * (2.f - msv);
    meanl[tid] = msv * m;
    rstdl[tid] = rsqrtf(var + kEps);
    wl2[tid] = w[tid];
    bl2[tid] = b[tid];
  }
  __syncthreads();
  const int node = blockIdx.x * 256 + tid;
  if (node >= kN) return;
  float* op = out + (size_t)node * kT;
#pragma unroll
  for (int o4 = 0; o4 < kT / 4; ++o4) {
    float4 v = *reinterpret_cast<const float4*>(op + o4 * 4);
    float r[4] = {v.x, v.y, v.z, v.w};
#pragma unroll
    for (int j = 0; j < 4; ++j) {
      int o = o4 * 4 + j;
      r[j] = fmaxf((r[j] - meanl[o]) * rstdl[o] * wl2[o] + bl2[o], 0.f);
    }
    *reinterpret_cast<float4*>(op + o4 * 4) =
        make_float4(r[0], r[1], r[2], r[3]);
  }
}

}  // namespace

extern "C" void kernel_launch(void* const* d_in, const int* in_sizes, int n_in,
                              void* d_out, int out_size, void* d_ws,
                              size_t ws_size, hipStream_t stream) {
  const float* x     = (const float*)d_in[0];
  const float* eattr = (const float*)d_in[1];
  const int*   eidx  = (const int*)d_in[2];
  const float* initW = (const float*)d_in[3];
  const float* initb = (const float*)d_in[4];
  const float* emW   = (const float*)d_in[5];
  const float* emb   = (const float*)d_in[6];
  const float* rW    = (const float*)d_in[7];
  const float* rb    = (const float*)d_in[8];
  const float* gnw   = (const float*)d_in[9];
  const float* gnb   = (const float*)d_in[10];
  const float* gnms  = (const float*)d_in[11];
  const float* tW    = (const float*)d_in[12];
  const float* tb    = (const float*)d_in[13];
  const float* fW    = (const float*)d_in[14];
  const float* fb    = (const float*)d_in[15];
  const float* fgw   = (const float*)d_in[16];
  const float* fgb   = (const float*)d_in[17];
  const float* fgms  = (const float*)d_in[18];
  float* out = (float*)d_out;

  // workspace layout (round-4)
  float* h     = (float*)d_ws;                       // kN*kH f32
  float* conv  = h + (size_t)kN * kH;                // kN*kH f32
  float* stats = conv + (size_t)kN * kH;             // 128 f32
  float* msg   = stats + 128;                        // kE*kH f32
  unsigned short* wbf = (unsigned short*)(msg + (size_t)kE * kH);  // 196 KB
  int* cnt    = (int*)(wbf + (size_t)kL * 64 * 64 * 8);  // kN
  int* off    = cnt + kN;                            // kN
  int* cursor = off + kN;                            // kN
  int* pos    = cursor + kN;                         // kE

  const int nodeBlocks = (kN + 255) / 256;           // 79
  const int edgeBlocks = kE / EB;                    // 1250
  const int aggBlocks  = (kN * 64 + 255) / 256;      // 5000 (wave per node)

  // one-time per call: group edges by dst
  hipMemsetAsync(cnt, 0, kN * sizeof(int), stream);
  hist_dst<<<(kE + 255) / 256, 256, 0, stream>>>(eidx, cnt);
  scan_nodes<<<1, 1024, 0, stream>>>(cnt, off, cursor);
  place_edges<<<(kE + 255) / 256, 256, 0, stream>>>(eidx, cursor, pos);

  pack_w<<<kL * 64 * 64 / 256, 256, 0, stream>>>(emW, wbf);
  init_proj<<<nodeBlocks, 256, 0, stream>>>(x, initW, initb, h);
  for (int l = 0; l < kL; ++l) {
    edge_msg_mfma<<<edgeBlocks, 256, 0, stream>>>(
        eattr, eidx, pos, h, wbf + (size_t)l * 64 * 64 * 8,
        emb + (size_t)l * kH * kH, msg);
    agg_nodes<<<aggBlocks, 256, 0, stream>>>(msg, off, cnt, conv);
    hipMemsetAsync(stats, 0, 2 * kH * sizeof(float), stream);
    root_stats<<<nodeBlocks, 256, 0, stream>>>(
        h, rW + (size_t)l * kH * kH, rb + l * kH, conv, stats);
    norm_trans<<<nodeBlocks, 256, 0, stream>>>(
        conv, stats, gnw + l * kH, gnb + l * kH, gnms + l * kH,
        tW + (size_t)l * 2 * kH * kH, tb + l * kH, h);
  }
  hipMemsetAsync(stats, 0, 2 * kT * sizeof(float), stream);
  final_lin<<<nodeBlocks, 256, 0, stream>>>(h, fW, fb, out, stats);
  final_norm<<<nodeBlocks, 256, 0, stream>>>(stats, fgw, fgb, fgms, out);
}